// Round 12
// baseline (229.116 us; speedup 1.0000x reference)
//
#include <hip/hip_runtime.h>

// ContractExpand via bf16 MFMA — persistent M-tile pipeline for r=1,2:
//   out[n,b,l,:] = relu(seg_r(x)[b, l/r, :] @ W[n]^T + bias[n]) / r,  r={25,10,4,2,1}
// r=1,2: block owns 4 consecutive 32-row tiles; loop per tile:
//   issue next tile's x-loads (reg stage, T14) -> MFMA(cur) -> bar ->
//   ds_write next A + bf16 cout into freed buffer -> bar -> expanded stores
//   (stores overlap next tile's MFMA).  2 barriers/tile, seg dbuf 2x20 KB.
// r=4,10,25: classic single-tile body (r10 structure, bf16 cout in buf1).

typedef short bf16x8 __attribute__((ext_vector_type(8)));
typedef short bf16x4 __attribute__((ext_vector_type(4)));
typedef float f32x4  __attribute__((ext_vector_type(4)));

namespace {
constexpr int D    = 300;
constexpr int LSEQ = 800;
constexpr int KP   = 320;    // padded K (10 steps of 32)
constexpr int NP   = 320;    // padded N rows of Wb
constexpr int CB   = 308;    // bf16 cout row stride (shorts); 4-row groups hit
                             // disjoint bank octets (616B*4 = 2464B ≡ 8 mod 32)
constexpr int BUF  = 20480;  // one seg buffer (32 rows * 640 B)
constexpr int SMEM_BYTES = 2 * BUF;   // 40960
}

__device__ __forceinline__ unsigned short f2bf(float f) {
  unsigned u = __float_as_uint(f);
  u += 0x7fffu + ((u >> 16) & 1u);   // RNE
  return (unsigned short)(u >> 16);
}
__device__ __forceinline__ float bf2f(short s) {
  return __uint_as_float(((unsigned)(unsigned short)s) << 16);
}

__global__ __launch_bounds__(256)
void convert_w(const float* __restrict__ W, short* __restrict__ Wb) {
  const int item = blockIdx.x * 256 + threadIdx.x;   // 64000 items
  if (item >= 5 * NP * KP / 8) return;
  const int off = item * 8;
  const int n   = off / (NP * KP);
  const int rem = off - n * (NP * KP);
  const int c   = rem / KP;
  const int k0  = rem - c * KP;
  float s[8];
  #pragma unroll
  for (int j = 0; j < 8; ++j) s[j] = 0.f;
  if (c < D) {
    const float* wp = W + (size_t)n * D * D + (size_t)c * D + k0;
    if (k0 < 296) {
      const float4 v0 = *(const float4*)(wp);
      const float4 v1 = *(const float4*)(wp + 4);
      s[0] = v0.x; s[1] = v0.y; s[2] = v0.z; s[3] = v0.w;
      s[4] = v1.x; s[5] = v1.y; s[6] = v1.z; s[7] = v1.w;
    } else if (k0 == 296) {
      const float4 v0 = *(const float4*)(wp);
      s[0] = v0.x; s[1] = v0.y; s[2] = v0.z; s[3] = v0.w;
    }
  }
  bf16x8 p;
  #pragma unroll
  for (int j = 0; j < 8; ++j) p[j] = (short)f2bf(s[j]);
  *(bf16x8*)(Wb + (size_t)off) = p;
}

// ---- shared pieces ------------------------------------------------------

// expanded f32 stores from a bf16 cout tile in LDS
template<int N, int R, int G>
__device__ __forceinline__ void store_expanded(const short* __restrict__ cout,
    const int m0, float* __restrict__ out) {
  const int tid = threadIdx.x;
  constexpr int TOTAL = 32 * R * 75;
  for (int i = tid; i < TOTAL; i += 256) {
    const int rowrep = i / 75;
    const int chunk  = i - rowrep * 75;
    const int ml     = rowrep / R;
    const int q      = rowrep - ml * R;
    const int m      = m0 + ml;
    const int bb     = m / G;
    const int grp    = m - bb * G;
    const bf16x4 sv = *(const bf16x4*)(cout + ml * CB + chunk * 4);
    f32x4 v;
    v[0] = bf2f(sv[0]); v[1] = bf2f(sv[1]); v[2] = bf2f(sv[2]); v[3] = bf2f(sv[3]);
    float* __restrict__ op =
        out + ((size_t)((N * 64 + bb) * LSEQ) + grp * R + q) * D + chunk * 4;
    *(f32x4*)op = v;
  }
}

// MFMA over seg buffer at `smem` (32x320 bf16, XOR-swizzled), B from global W
template<int N>
__device__ __forceinline__ void mfma_tile(const char* __restrict__ smem,
    const short* __restrict__ wp[5], f32x4 acc[2][5]) {
  const int lane = threadIdx.x & 63;
  const int cr   = lane & 15;
  const int kh   = lane >> 4;
  const int swz0 = (cr & 7) << 4;
  const int abase0 = cr * 640        + kh * 16;
  const int abase1 = (16 + cr) * 640 + kh * 16;

  bf16x8 bpre[5];
  #pragma unroll
  for (int t = 0; t < 5; ++t) bpre[t] = *(const bf16x8*)(wp[t]);
  bf16x8 a0pre = *(const bf16x8*)(smem + (abase0 ^ swz0));
  bf16x8 a1pre = *(const bf16x8*)(smem + (abase1 ^ swz0));

  #pragma unroll
  for (int ks = 0; ks < 10; ++ks) {
    bf16x8 bcur[5];
    #pragma unroll
    for (int t = 0; t < 5; ++t) bcur[t] = bpre[t];
    const bf16x8 a0 = a0pre, a1 = a1pre;
    if (ks < 9) {
      #pragma unroll
      for (int t = 0; t < 5; ++t) bpre[t] = *(const bf16x8*)(wp[t] + (ks + 1) * 32);
      a0pre = *(const bf16x8*)(smem + ((abase0 + (ks + 1) * 64) ^ swz0));
      a1pre = *(const bf16x8*)(smem + ((abase1 + (ks + 1) * 64) ^ swz0));
    }
    #pragma unroll
    for (int t = 0; t < 5; ++t) {
      acc[0][t] = __builtin_amdgcn_mfma_f32_16x16x32_bf16(a0, bcur[t], acc[0][t], 0, 0, 0);
      acc[1][t] = __builtin_amdgcn_mfma_f32_16x16x32_bf16(a1, bcur[t], acc[1][t], 0, 0, 0);
    }
  }
}

// bias+relu+/R from acc -> bf16 cout tile
template<int N, int R>
__device__ __forceinline__ void write_cout(short* __restrict__ cout,
    f32x4 acc[2][5], const float bv[5]) {
  const int lane = threadIdx.x & 63;
  const int wv   = threadIdx.x >> 6;
  const int cr   = lane & 15;
  const int kh   = lane >> 4;
  const float inv_r = 1.0f / (float)R;
  #pragma unroll
  for (int t = 0; t < 5; ++t) {
    const int col = (wv * 5 + t) * 16 + cr;
    if (col < D) {
      #pragma unroll
      for (int mt = 0; mt < 2; ++mt)
        #pragma unroll
        for (int j = 0; j < 4; ++j) {
          const int row = mt * 16 + kh * 4 + j;
          cout[row * CB + col] =
              (short)f2bf(fmaxf(acc[mt][t][j] + bv[t], 0.f) * inv_r);
        }
    }
  }
}

// ---- persistent body for r = 1, 2 (TPB consecutive tiles) ----------------

template<int N, int R, int G, int TPB>
__device__ __forceinline__ void ce_persist(const int base, char* __restrict__ smem,
    const float* __restrict__ x, const short* __restrict__ Wb,
    const float* __restrict__ bias, float* __restrict__ out) {
  const int tid  = threadIdx.x;
  const int wv   = tid >> 6;
  const int lane = tid & 63;
  const int cr   = lane & 15;
  const int kh   = lane >> 4;

  const short* __restrict__ Wn = Wb + (size_t)N * NP * KP;
  const short* __restrict__ wp[5];
  #pragma unroll
  for (int t = 0; t < 5; ++t)
    wp[t] = Wn + (size_t)((wv * 5 + t) * 16 + cr) * KP + kh * 8;
  float bv[5];
  #pragma unroll
  for (int t = 0; t < 5; ++t) {
    const int col = (wv * 5 + t) * 16 + cr;
    bv[t] = (col < D) ? bias[N * D + col] : 0.f;
  }

  // per-thread stage state: 5 items x R rows x 2 float4
  float4 v0[5 * R], v1[5 * R];
  int srow[5], sk0[5];
  #pragma unroll
  for (int it = 0; it < 5; ++it) {
    const int cidx = tid + it * 256;
    srow[it] = cidx / 40;
    sk0[it]  = (cidx - srow[it] * 40) * 8;
  }

  // ---- stage issue: global loads for tile `tile` ----
  auto stage_issue = [&](int m0) {
    #pragma unroll
    for (int it = 0; it < 5; ++it) {
      const int k0 = sk0[it];
      if (k0 < D) {
        const int m   = m0 + srow[it];
        const int bb  = m / G;
        const int grp = m - bb * G;
        const float* xp = x + ((size_t)(bb * LSEQ + grp * R)) * D + k0;
        #pragma unroll
        for (int q = 0; q < R; ++q) {
          v0[it * R + q] = *(const float4*)(xp + (size_t)q * D);
          v1[it * R + q] = (k0 < 296) ? *(const float4*)(xp + (size_t)q * D + 4)
                                      : (float4){0.f, 0.f, 0.f, 0.f};
        }
      }
    }
  };
  // ---- stage consume: sum, pack bf16, ds_write into buffer `buf` ----
  auto stage_consume = [&](char* buf) {
    #pragma unroll
    for (int it = 0; it < 5; ++it) {
      const int k0  = sk0[it];
      const int row = srow[it];
      float s[8];
      #pragma unroll
      for (int j = 0; j < 8; ++j) s[j] = 0.f;
      if (k0 < D) {
        #pragma unroll
        for (int q = 0; q < R; ++q) {
          s[0] += v0[it * R + q].x; s[1] += v0[it * R + q].y;
          s[2] += v0[it * R + q].z; s[3] += v0[it * R + q].w;
          s[4] += v1[it * R + q].x; s[5] += v1[it * R + q].y;
          s[6] += v1[it * R + q].z; s[7] += v1[it * R + q].w;
        }
      }
      bf16x8 p;
      #pragma unroll
      for (int j = 0; j < 8; ++j) p[j] = (short)f2bf(s[j]);
      const int boff = (row * 640 + k0 * 2) ^ ((row & 7) << 4);
      *(bf16x8*)(buf + boff) = p;
    }
  };

  // prologue: stage tile 0
  stage_issue(base * TPB * 32);
  stage_consume(smem);
  __syncthreads();

  for (int t = 0; t < TPB; ++t) {
    char* curb = smem + (t & 1) * BUF;
    char* nxtb = smem + ((t + 1) & 1) * BUF;
    const int m0 = (base * TPB + t) * 32;

    if (t + 1 < TPB) stage_issue((base * TPB + t + 1) * 32);  // in flight

    f32x4 acc[2][5];
    #pragma unroll
    for (int mt = 0; mt < 2; ++mt)
      #pragma unroll
      for (int tt = 0; tt < 5; ++tt) acc[mt][tt] = (f32x4){0.f, 0.f, 0.f, 0.f};
    mfma_tile<N>(curb, wp, acc);

    __syncthreads();                       // MFMA(t) done, stores(t-1) done
    if (t + 1 < TPB) stage_consume(nxtb);  // next A into freed A-buffer
    write_cout<N, R>((short*)curb, acc, bv);
    __syncthreads();                       // writes visible

    store_expanded<N, R, G>((const short*)curb, m0, out);  // overlaps next MFMA
  }
}

// ---- classic single-tile body for r = 4, 10, 25 --------------------------

template<int N, int R, int G>
__device__ __forceinline__ void ce_classic(const int tile, char* __restrict__ smem,
    const float* __restrict__ x, const short* __restrict__ Wb,
    const float* __restrict__ bias, float* __restrict__ out) {
  const int tid = threadIdx.x;
  const int m0  = tile * 32;
  constexpr int BQ = (R <= 5) ? R : 5;

  #pragma unroll
  for (int it = 0; it < 5; ++it) {
    const int cidx = tid + it * 256;
    const int row  = cidx / 40;
    const int k0   = (cidx - row * 40) * 8;
    float s[8];
    #pragma unroll
    for (int j = 0; j < 8; ++j) s[j] = 0.f;
    if (k0 < D) {
      const int m   = m0 + row;
      const int bb  = m / G;
      const int grp = m - bb * G;
      const float* xp = x + ((size_t)(bb * LSEQ + grp * R)) * D + k0;
      if (k0 <= D - 8) {
        for (int qb = 0; qb < R; qb += BQ) {
          float4 a0[BQ], a1[BQ];
          #pragma unroll
          for (int j = 0; j < BQ; ++j) {
            a0[j] = *(const float4*)(xp + (size_t)(qb + j) * D);
            a1[j] = *(const float4*)(xp + (size_t)(qb + j) * D + 4);
          }
          #pragma unroll
          for (int j = 0; j < BQ; ++j) {
            s[0] += a0[j].x; s[1] += a0[j].y; s[2] += a0[j].z; s[3] += a0[j].w;
            s[4] += a1[j].x; s[5] += a1[j].y; s[6] += a1[j].z; s[7] += a1[j].w;
          }
        }
      } else {
        for (int qb = 0; qb < R; qb += BQ) {
          float4 a0[BQ];
          #pragma unroll
          for (int j = 0; j < BQ; ++j)
            a0[j] = *(const float4*)(xp + (size_t)(qb + j) * D);
          #pragma unroll
          for (int j = 0; j < BQ; ++j) {
            s[0] += a0[j].x; s[1] += a0[j].y; s[2] += a0[j].z; s[3] += a0[j].w;
          }
        }
      }
    }
    bf16x8 p;
    #pragma unroll
    for (int j = 0; j < 8; ++j) p[j] = (short)f2bf(s[j]);
    const int boff = (row * 640 + k0 * 2) ^ ((row & 7) << 4);
    *(bf16x8*)(smem + boff) = p;
  }

  const int wv   = tid >> 6;
  const int lane = tid & 63;
  const int cr   = lane & 15;
  const int kh   = lane >> 4;
  const short* __restrict__ Wn = Wb + (size_t)N * NP * KP;
  const short* __restrict__ wp[5];
  #pragma unroll
  for (int t = 0; t < 5; ++t)
    wp[t] = Wn + (size_t)((wv * 5 + t) * 16 + cr) * KP + kh * 8;
  float bv[5];
  #pragma unroll
  for (int t = 0; t < 5; ++t) {
    const int col = (wv * 5 + t) * 16 + cr;
    bv[t] = (col < D) ? bias[N * D + col] : 0.f;
  }
  __syncthreads();

  f32x4 acc[2][5];
  #pragma unroll
  for (int mt = 0; mt < 2; ++mt)
    #pragma unroll
    for (int t = 0; t < 5; ++t) acc[mt][t] = (f32x4){0.f, 0.f, 0.f, 0.f};
  mfma_tile<N>(smem, wp, acc);
  __syncthreads();

  short* cout = (short*)(smem + BUF);        // buf1
  write_cout<N, R>(cout, acc, bv);
  __syncthreads();

  store_expanded<N, R, G>(cout, m0, out);
}

__global__ __launch_bounds__(256, 2)
void ce_mfma12(const float* __restrict__ x, const short* __restrict__ Wb,
               const float* __restrict__ bias, float* __restrict__ out) {
  __shared__ __align__(16) char smem[SMEM_BYTES];
  const int bid = blockIdx.x;                // heavy-r first
  if (bid < 64)        ce_classic<4, 25, 32 >(bid,        smem, x, Wb, bias, out);
  else if (bid < 224)  ce_classic<3, 10, 80 >(bid - 64,   smem, x, Wb, bias, out);
  else if (bid < 624)  ce_classic<2, 4, 200 >(bid - 224,  smem, x, Wb, bias, out);
  else if (bid < 824)  ce_persist<1, 2, 400, 4>(bid - 624, smem, x, Wb, bias, out);
  else                 ce_persist<0, 1, 800, 4>(bid - 824, smem, x, Wb, bias, out);
}

extern "C" void kernel_launch(void* const* d_in, const int* in_sizes, int n_in,
                              void* d_out, int out_size, void* d_ws, size_t ws_size,
                              hipStream_t stream) {
  const float* x    = (const float*)d_in[0];  // [64, 800, 300]
  const float* W    = (const float*)d_in[1];  // [5, 300, 300]
  const float* bias = (const float*)d_in[2];  // [5, 300]
  float* out        = (float*)d_out;          // [5, 64, 800, 300]
  short* Wb         = (short*)d_ws;           // [5][320][320] bf16, ~1 MB

  convert_w<<<250, 256, 0, stream>>>(W, Wb);
  // 64 r25 + 160 r10 + 400 r4 + 200 r2-persist(x4) + 400 r1-persist(x4) = 1224
  ce_mfma12<<<1224, 256, 0, stream>>>(x, Wb, bias, out);
}